// Round 9
// baseline (267.022 us; speedup 1.0000x reference)
//
#include <hip/hip_runtime.h>
#include <hip/hip_fp16.h>

#define VOX (128 * 128 * 128)   // 2097152
#define P 130                   // padded dim
#define PP (P * P)              // 16900
#define PVOX (P * P * P)        // 2197000

typedef unsigned short u16;
typedef _Float16 f16x2 __attribute__((ext_vector_type(2)));
typedef _Float16 f16x8 __attribute__((ext_vector_type(8)));
typedef __attribute__((ext_vector_type(4))) float f32x4;
typedef __attribute__((ext_vector_type(2))) float f32x2;

__device__ __forceinline__ u16 f2h(float f) {
    return __builtin_bit_cast(unsigned short, (_Float16)f);
}
__device__ __forceinline__ unsigned pkh_relu(float a, float b) {
    float ra = a > 0.f ? a : 0.f, rb = b > 0.f ? b : 0.f;
    return (unsigned)f2h(ra) | ((unsigned)f2h(rb) << 16);
}
__device__ __forceinline__ f16x2 h2(unsigned u) { return __builtin_bit_cast(f16x2, u); }

// dot2: acc += a.x*b.x + a.y*b.y  (f32 accumulate, single V_DOT2_F32_F16)
__device__ __forceinline__ float dot2(unsigned a, unsigned b, float c) {
#if __has_builtin(__builtin_amdgcn_fdot2)
    return __builtin_amdgcn_fdot2(h2(a), h2(b), c, false);
#else
    f16x2 av = h2(a), bv = h2(b);
    c = fmaf((float)av.x, (float)bv.x, c);
    return fmaf((float)av.y, (float)bv.y, c);
#endif
}

// fast tanh: 1 - 2/(1+e^{2x})
__device__ __forceinline__ float fast_tanh(float x) {
    float e = __expf(2.0f * x);
    return 1.0f - 2.0f * __builtin_amdgcn_rcpf(1.0f + e);
}

// setup: zero halo shells of x1/x2 + build weight tables.
// w2frag[((dx*3+s)*64+lane)*8+j] = f16(w2[oc=lane&15][ic=j][dzdy=s*4+(lane>>4), dx]),
//   0 if dzdy>8  (dzdy = dz*3+dy; tap = dzdy*3+dx)
// w3p[tap*8+j] = packed f16 pair (w3[2j][tap], w3[2j+1][tap])
// w1p[tap*4+j] = float2 (w1[2j][tap], w1[2j+1][tap])
__global__ __launch_bounds__(256) void setup_kernel(
    const float* __restrict__ w1, const float* __restrict__ w2,
    const float* __restrict__ w3, u16* __restrict__ w2frag,
    unsigned* __restrict__ w3p, float2* __restrict__ w1p,
    u16* __restrict__ x1, u16* __restrict__ x2) {
    int i = blockIdx.x * 256 + threadIdx.x;
    if (i < 4608) {
        int j = i & 7, l = (i >> 3) & 63, g = i >> 9;  // g = dx*3+s
        int s = g % 3, dx = g / 3;
        int q = l >> 4, oc = l & 15;
        int dzdy = s * 4 + q;
        float v = (dzdy < 9) ? w2[(oc * 8 + j) * 27 + dzdy * 3 + dx] : 0.0f;
        w2frag[i] = f2h(v);
    }
    if (i < 216) {
        int tap = i >> 3, j = i & 7;
        w3p[i] = (unsigned)f2h(w3[(2 * j) * 27 + tap]) |
                 ((unsigned)f2h(w3[(2 * j + 1) * 27 + tap]) << 16);
    }
    if (i < 108) {
        int tap = i >> 2, j = i & 3;
        w1p[i] = make_float2(w1[(2 * j) * 27 + tap], w1[(2 * j + 1) * 27 + tap]);
    }
    if (i >= PVOX) return;
    int d = i / PP;
    int r = i - d * PP;
    int h = r / P;
    int w = r - h * P;
    if (d == 0 || d == P - 1 || h == 0 || h == P - 1 || w == 0 || w == P - 1) {
        uint4 z = {0u, 0u, 0u, 0u};
        *(uint4*)(x1 + (size_t)i * 8) = z;
        *(uint4*)(x2 + (size_t)i * 16) = z;
        *(uint4*)(x2 + (size_t)i * 16 + 8) = z;
    }
}

// integrate: x0 padded f16 [130^3] = cube * (1 + 0.1*sin(2pi*(d+h+w)/384)), halo = 0
__global__ __launch_bounds__(256) void integrate_kernel(
    const float* __restrict__ in, u16* __restrict__ x0) {
    int i = blockIdx.x * 256 + threadIdx.x;
    if (i >= PVOX) return;
    int d = i / PP;
    int r = i - d * PP;
    int h = r / P;
    int w = r - h * P;
    float v = 0.0f;
    if (d >= 1 && d <= 128 && h >= 1 && h <= 128 && w >= 1 && w <= 128) {
        int s = (d - 1) + (h - 1) + (w - 1);
        float fld = 1.0f + 0.1f * sinf(6.283185307179586f * (float)s / 384.0f);
        v = in[(size_t)(d - 1) * 16384 + (h - 1) * 128 + (w - 1)] * fld;
    }
    x0[i] = f2h(v);
}

// conv1: x0 padded f16 [130^3] -> x1 f16 channels-last padded [130^3][8], relu.
// Strip 4(h) x 2(w) voxels/thread; per (dz, r in 0..5): one 4-f16 window load.
__global__ __launch_bounds__(256) void conv1_kernel(
    const u16* __restrict__ x0, const float2* __restrict__ w1p,
    const float* __restrict__ b1, u16* __restrict__ x1) {
    const int t = blockIdx.x * 256 + threadIdx.x;  // VOX/8 threads
    const int w0 = (t & 63) * 2;
    const int h0 = ((t >> 6) & 31) * 4;
    const int d = t >> 11;

    f32x2 acc[4][4][2];  // [i][jpair][vox]
#pragma unroll
    for (int j = 0; j < 4; ++j) {
        const f32x2 b = {b1[2 * j], b1[2 * j + 1]};
#pragma unroll
        for (int i = 0; i < 4; ++i) { acc[i][j][0] = b; acc[i][j][1] = b; }
    }

#pragma unroll
    for (int dz = 0; dz < 3; ++dz) {
        const u16* zb = x0 + (size_t)(d + dz) * PP + (size_t)h0 * P + w0;
        const float2* wz = w1p + dz * 9 * 4;
#pragma unroll
        for (int r = 0; r < 6; ++r) {
            const u16* rp = zb + r * P;
            const unsigned u0 = *(const unsigned*)rp;
            const unsigned u1 = *(const unsigned*)(rp + 2);
            float vv[4];
            vv[0] = (float)h2(u0).x; vv[1] = (float)h2(u0).y;
            vv[2] = (float)h2(u1).x; vv[3] = (float)h2(u1).y;
#pragma unroll
            for (int dy = 0; dy < 3; ++dy) {
                const int i = r - dy;
                if (i < 0 || i > 3) continue;  // resolved at compile time
#pragma unroll
                for (int dx = 0; dx < 3; ++dx) {
                    const f32x2 s0 = {vv[dx], vv[dx]};
                    const f32x2 s1 = {vv[dx + 1], vv[dx + 1]};
#pragma unroll
                    for (int j = 0; j < 4; ++j) {
                        const float2 wraw = wz[(dy * 3 + dx) * 4 + j];
                        const f32x2 wv = {wraw.x, wraw.y};
                        acc[i][j][0] = __builtin_elementwise_fma(wv, s0, acc[i][j][0]);
                        acc[i][j][1] = __builtin_elementwise_fma(wv, s1, acc[i][j][1]);
                    }
                }
            }
        }
    }
    const size_t e0 = ((size_t)(d + 1) * P + (h0 + 1)) * P + (w0 + 1);
#pragma unroll
    for (int i = 0; i < 4; ++i) {
        uint4 oA, oB;
        oA.x = pkh_relu(acc[i][0][0].x, acc[i][0][0].y);
        oA.y = pkh_relu(acc[i][1][0].x, acc[i][1][0].y);
        oA.z = pkh_relu(acc[i][2][0].x, acc[i][2][0].y);
        oA.w = pkh_relu(acc[i][3][0].x, acc[i][3][0].y);
        oB.x = pkh_relu(acc[i][0][1].x, acc[i][0][1].y);
        oB.y = pkh_relu(acc[i][1][1].x, acc[i][1][1].y);
        oB.z = pkh_relu(acc[i][2][1].x, acc[i][2][1].y);
        oB.w = pkh_relu(acc[i][3][1].x, acc[i][3][1].y);
        *(uint4*)(x1 + (e0 + (size_t)i * P) * 8) = oA;
        *(uint4*)(x1 + (e0 + (size_t)i * P + 1) * 8) = oB;
    }
}

// conv2: dx-FACTORED implicit-GEMM MFMA. A = weights (M=16 oc), B = acts (N=16 vox).
// K = (dzdy)x(ic) = 72 padded to 96 (3 k-steps); each act load (one (dz,dy) row,
// no dx offset) feeds THREE mfmas (dx=0,1,2 weight tables) -> act loads 24/wave
// (was 56). acc_dx[p] = sum_{dzdy,ic} w2[oc][ic][dzdy,dx] * x1[p];
// out[v] = b + acc_1[v] + acc_0[v-1] + acc_2[v+1]  (voxel shifts done via
// intra-wave shuffles over mi; row-edge terms are exactly 0 by the zero halo).
__global__ __launch_bounds__(256) void conv2_mfma_kernel(
    const u16* __restrict__ x1, const u16* __restrict__ w2frag,
    const float* __restrict__ b2, u16* __restrict__ x2) {
    const int lane = threadIdx.x & 63;
    const int row = blockIdx.x * 4 + (threadIdx.x >> 6);
    const int q = lane >> 4;
    const int mi = lane & 15;
    const int d0 = row >> 7;
    const int h0 = row & 127;

    f32x4 acc[8][3];
#pragma unroll
    for (int t = 0; t < 8; ++t)
#pragma unroll
        for (int dx = 0; dx < 3; ++dx) acc[t][dx] = (f32x4){0.f, 0.f, 0.f, 0.f};

#pragma unroll
    for (int s = 0; s < 3; ++s) {
        int dzdy = s * 4 + q;
        if (dzdy > 8) dzdy = 8;  // pad rows: weights are zero there
        const int dz = dzdy / 3;
        const int dy = dzdy - dz * 3;
        const u16* bp = x1 + ((size_t)((d0 + dz) * P + (h0 + dy)) * P + (mi + 1)) * 8;
        f16x8 wf[3];
#pragma unroll
        for (int dx = 0; dx < 3; ++dx)
            wf[dx] = *(const f16x8*)(w2frag + (size_t)((dx * 3 + s) * 64 + lane) * 8);
        f16x8 a[8];
#pragma unroll
        for (int t = 0; t < 8; ++t) a[t] = *(const f16x8*)(bp + t * 128);
#pragma unroll
        for (int t = 0; t < 8; ++t) {
#pragma unroll
            for (int dx = 0; dx < 3; ++dx)
                acc[t][dx] = __builtin_amdgcn_mfma_f32_16x16x32_f16(wf[dx], a[t], acc[t][dx], 0, 0, 0);
        }
    }

    // epilogue: combine shifted accs. D: row(oc)=q*4+r, col(voxel)=mi.
    const float4 bv = *(const float4*)(b2 + q * 4);
    const size_t obase = ((size_t)(d0 + 1) * P + (h0 + 1)) * P + 1;
    const int hi_lane = (lane & 48) + 15;  // own quad, mi=15
    const int lo_lane = (lane & 48);       // own quad, mi=0
#pragma unroll
    for (int t = 0; t < 8; ++t) {
        const int tm = (t > 0) ? t - 1 : 0;
        const int tp = (t < 7) ? t + 1 : 7;
        float res[4];
#pragma unroll
        for (int c = 0; c < 4; ++c) {
            const float up = __shfl_up(acc[t][0][c], 1, 16);
            const float pu = (t > 0) ? __shfl(acc[tm][0][c], hi_lane, 64) : 0.0f;
            const float A0 = (mi == 0) ? pu : up;
            const float dn = __shfl_down(acc[t][2][c], 1, 16);
            const float pd = (t < 7) ? __shfl(acc[tp][2][c], lo_lane, 64) : 0.0f;
            const float A2 = (mi == 15) ? pd : dn;
            res[c] = acc[t][1][c] + A0 + A2;
        }
        uint2 o;
        o.x = pkh_relu(res[0] + bv.x, res[1] + bv.y);
        o.y = pkh_relu(res[2] + bv.z, res[3] + bv.w);
        *(uint2*)(x2 + (obase + 16 * t + mi) * 16 + q * 4) = o;
    }
}

// conv3: padded x2 [130^3][16] f16 -> out fp32 [128^3] (one batch), tanh.
// 2(d) x 8(h) strip per thread: dz AND dy sharing; per (z-row, h-row) one
// 3-chunk window (6 b128, 96B) consumed immediately. 240B/voxel issued.
__global__ __launch_bounds__(256) void conv3_kernel(
    const u16* __restrict__ x2, const unsigned* __restrict__ w3p,
    const float* __restrict__ b3, float* __restrict__ out) {
    const int t = blockIdx.x * 256 + threadIdx.x;  // VOX/16 threads
    const int w = t & 127;
    const int h0 = ((t >> 7) & 15) * 8;
    const int d0 = (t >> 11) * 2;

    float accA[2][8], accB[2][8];
#pragma unroll
    for (int dd = 0; dd < 2; ++dd)
#pragma unroll
        for (int i = 0; i < 8; ++i) { accA[dd][i] = 0.f; accB[dd][i] = 0.f; }

#pragma unroll 1
    for (int z = 0; z < 4; ++z) {  // padded z-row = d0 + z
        const u16* zb = x2 + ((size_t)((d0 + z) * P + h0) * P + w) * 16;
#pragma unroll
        for (int r = 0; r < 10; ++r) {
            const u16* rp = zb + (size_t)r * (P * 16);
            const uint4 c0l = *(const uint4*)(rp);
            const uint4 c0h = *(const uint4*)(rp + 8);
            const uint4 c1l = *(const uint4*)(rp + 16);
            const uint4 c1h = *(const uint4*)(rp + 24);
            const uint4 c2l = *(const uint4*)(rp + 32);
            const uint4 c2h = *(const uint4*)(rp + 40);
#pragma unroll
            for (int dd = 0; dd < 2; ++dd) {
                const int dz = z - dd;
                if (dz < 0 || dz > 2) continue;  // wave-uniform runtime guard
                const unsigned* wz = w3p + dz * 9 * 8;
#pragma unroll
                for (int dy = 0; dy < 3; ++dy) {
                    const int i = r - dy;
                    if (i < 0 || i > 7) continue;  // compile-time after unroll
                    const unsigned* wp = wz + dy * 3 * 8;
                    float a = accA[dd][i], b = accB[dd][i];
                    a = dot2(c0l.x, wp[0], a);  b = dot2(c0l.y, wp[1], b);
                    a = dot2(c0l.z, wp[2], a);  b = dot2(c0l.w, wp[3], b);
                    a = dot2(c0h.x, wp[4], a);  b = dot2(c0h.y, wp[5], b);
                    a = dot2(c0h.z, wp[6], a);  b = dot2(c0h.w, wp[7], b);
                    a = dot2(c1l.x, wp[8], a);  b = dot2(c1l.y, wp[9], b);
                    a = dot2(c1l.z, wp[10], a); b = dot2(c1l.w, wp[11], b);
                    a = dot2(c1h.x, wp[12], a); b = dot2(c1h.y, wp[13], b);
                    a = dot2(c1h.z, wp[14], a); b = dot2(c1h.w, wp[15], b);
                    a = dot2(c2l.x, wp[16], a); b = dot2(c2l.y, wp[17], b);
                    a = dot2(c2l.z, wp[18], a); b = dot2(c2l.w, wp[19], b);
                    a = dot2(c2h.x, wp[20], a); b = dot2(c2h.y, wp[21], b);
                    a = dot2(c2h.z, wp[22], a); b = dot2(c2h.w, wp[23], b);
                    accA[dd][i] = a; accB[dd][i] = b;
                }
            }
        }
    }
    const float bias = b3[0];
#pragma unroll
    for (int dd = 0; dd < 2; ++dd) {
        const size_t obase = (size_t)((d0 + dd) * 128 + h0) * 128 + w;
#pragma unroll
        for (int i = 0; i < 8; ++i)
            out[obase + (size_t)i * 128] = fast_tanh(accA[dd][i] + accB[dd][i] + bias);
    }
}

extern "C" void kernel_launch(void* const* d_in, const int* in_sizes, int n_in,
                              void* d_out, int out_size, void* d_ws, size_t ws_size,
                              hipStream_t stream) {
    const float* cube = (const float*)d_in[0];
    const float* w1 = (const float*)d_in[1];
    const float* b1 = (const float*)d_in[2];
    const float* w2 = (const float*)d_in[3];
    const float* b2 = (const float*)d_in[4];
    const float* w3 = (const float*)d_in[5];
    const float* b3 = (const float*)d_in[6];
    float* out = (float*)d_out;

    // ws: w2frag@0 (9216B) | w3p@9216 (864B) | w1p@10080 (864B) | x0 @16384 | x1 | x2
    char* ws = (char*)d_ws;
    u16* w2frag = (u16*)ws;
    unsigned* w3p = (unsigned*)(ws + 9216);
    float2* w1p = (float2*)(ws + 10080);
    u16* x0 = (u16*)(ws + 16384);
    u16* x1 = (u16*)(ws + 16384 + (size_t)PVOX * sizeof(u16));
    u16* x2 = (u16*)(ws + 16384 + (size_t)PVOX * sizeof(u16) + (size_t)PVOX * 8 * sizeof(u16));

    setup_kernel<<<dim3((PVOX + 255) / 256), dim3(256), 0, stream>>>(
        w1, w2, w3, w2frag, w3p, w1p, x1, x2);

    for (int b = 0; b < 2; ++b) {
        integrate_kernel<<<dim3((PVOX + 255) / 256), dim3(256), 0, stream>>>(
            cube + (size_t)b * VOX, x0);
        conv1_kernel<<<dim3(VOX / 8 / 256), dim3(256), 0, stream>>>(x0, w1p, b1, x1);
        conv2_mfma_kernel<<<dim3(128 * 128 / 4), dim3(256), 0, stream>>>(x1, w2frag, b2, x2);
        conv3_kernel<<<dim3(VOX / 16 / 256), dim3(256), 0, stream>>>(
            x2, w3p, b3, out + (size_t)b * VOX);
    }
}

// Round 10
// 249.571 us; speedup vs baseline: 1.0699x; 1.0699x over previous
//
#include <hip/hip_runtime.h>
#include <hip/hip_fp16.h>

#define VOX (128 * 128 * 128)   // 2097152
#define P 130                   // padded dim
#define PP (P * P)              // 16900
#define PVOX (P * P * P)        // 2197000
#define LROW 130
#define NR 18                   // 3 dz * 6 h-rows staged per block

typedef unsigned short u16;
typedef _Float16 f16x2 __attribute__((ext_vector_type(2)));
typedef _Float16 f16x8 __attribute__((ext_vector_type(8)));
typedef __attribute__((ext_vector_type(4))) float f32x4;
typedef __attribute__((ext_vector_type(2))) float f32x2;

__device__ __forceinline__ u16 f2h(float f) {
    return __builtin_bit_cast(unsigned short, (_Float16)f);
}
__device__ __forceinline__ unsigned pkh_relu(float a, float b) {
    float ra = a > 0.f ? a : 0.f, rb = b > 0.f ? b : 0.f;
    return (unsigned)f2h(ra) | ((unsigned)f2h(rb) << 16);
}
__device__ __forceinline__ f16x2 h2(unsigned u) { return __builtin_bit_cast(f16x2, u); }

// dot2: acc += a.x*b.x + a.y*b.y  (f32 accumulate, single V_DOT2_F32_F16)
__device__ __forceinline__ float dot2(unsigned a, unsigned b, float c) {
#if __has_builtin(__builtin_amdgcn_fdot2)
    return __builtin_amdgcn_fdot2(h2(a), h2(b), c, false);
#else
    f16x2 av = h2(a), bv = h2(b);
    c = fmaf((float)av.x, (float)bv.x, c);
    return fmaf((float)av.y, (float)bv.y, c);
#endif
}

// fast tanh: 1 - 2/(1+e^{2x})
__device__ __forceinline__ float fast_tanh(float x) {
    float e = __expf(2.0f * x);
    return 1.0f - 2.0f * __builtin_amdgcn_rcpf(1.0f + e);
}

// setup: zero halo shells of x1/x2 + build weight tables (tap-major w2frag).
// w2frag[(s*64+lane)*8+j] = f16(w2[oc=lane&15][ic=j][tap=s*4+(lane>>4)]), 0 if tap>26
// w3p[tap*8+j] = packed f16 pair (w3[2j][tap], w3[2j+1][tap])
// w1p[tap*4+j] = float2 (w1[2j][tap], w1[2j+1][tap])
__global__ __launch_bounds__(256) void setup_kernel(
    const float* __restrict__ w1, const float* __restrict__ w2,
    const float* __restrict__ w3, u16* __restrict__ w2frag,
    unsigned* __restrict__ w3p, float2* __restrict__ w1p,
    u16* __restrict__ x1, u16* __restrict__ x2) {
    int i = blockIdx.x * 256 + threadIdx.x;
    if (i < 3584) {
        int j = i & 7, l = (i >> 3) & 63, s = i >> 9;
        int tap = s * 4 + (l >> 4), oc = l & 15;
        float v = (tap < 27) ? w2[(oc * 8 + j) * 27 + tap] : 0.0f;
        w2frag[i] = f2h(v);
    }
    if (i < 216) {
        int tap = i >> 3, j = i & 7;
        w3p[i] = (unsigned)f2h(w3[(2 * j) * 27 + tap]) |
                 ((unsigned)f2h(w3[(2 * j + 1) * 27 + tap]) << 16);
    }
    if (i < 108) {
        int tap = i >> 2, j = i & 3;
        w1p[i] = make_float2(w1[(2 * j) * 27 + tap], w1[(2 * j + 1) * 27 + tap]);
    }
    if (i >= PVOX) return;
    int d = i / PP;
    int r = i - d * PP;
    int h = r / P;
    int w = r - h * P;
    if (d == 0 || d == P - 1 || h == 0 || h == P - 1 || w == 0 || w == P - 1) {
        uint4 z = {0u, 0u, 0u, 0u};
        *(uint4*)(x1 + (size_t)i * 8) = z;
        *(uint4*)(x2 + (size_t)i * 16) = z;
        *(uint4*)(x2 + (size_t)i * 16 + 8) = z;
    }
}

// integrate: x0 padded f16 [130^3] = cube * (1 + 0.1*sin(2pi*(d+h+w)/384)), halo = 0
__global__ __launch_bounds__(256) void integrate_kernel(
    const float* __restrict__ in, u16* __restrict__ x0) {
    int i = blockIdx.x * 256 + threadIdx.x;
    if (i >= PVOX) return;
    int d = i / PP;
    int r = i - d * PP;
    int h = r / P;
    int w = r - h * P;
    float v = 0.0f;
    if (d >= 1 && d <= 128 && h >= 1 && h <= 128 && w >= 1 && w <= 128) {
        int s = (d - 1) + (h - 1) + (w - 1);
        float fld = 1.0f + 0.1f * sinf(6.283185307179586f * (float)s / 384.0f);
        v = in[(size_t)(d - 1) * 16384 + (h - 1) * 128 + (w - 1)] * fld;
    }
    x0[i] = f2h(v);
}

// conv1: x0 padded f16 [130^3] -> x1 f16 channels-last padded [130^3][8], relu.
// Strip 4(h) x 2(w) voxels/thread; per (dz, r in 0..5): one 4-f16 window load.
__global__ __launch_bounds__(256) void conv1_kernel(
    const u16* __restrict__ x0, const float2* __restrict__ w1p,
    const float* __restrict__ b1, u16* __restrict__ x1) {
    const int t = blockIdx.x * 256 + threadIdx.x;  // VOX/8 threads
    const int w0 = (t & 63) * 2;
    const int h0 = ((t >> 6) & 31) * 4;
    const int d = t >> 11;

    f32x2 acc[4][4][2];  // [i][jpair][vox]
#pragma unroll
    for (int j = 0; j < 4; ++j) {
        const f32x2 b = {b1[2 * j], b1[2 * j + 1]};
#pragma unroll
        for (int i = 0; i < 4; ++i) { acc[i][j][0] = b; acc[i][j][1] = b; }
    }

#pragma unroll
    for (int dz = 0; dz < 3; ++dz) {
        const u16* zb = x0 + (size_t)(d + dz) * PP + (size_t)h0 * P + w0;
        const float2* wz = w1p + dz * 9 * 4;
#pragma unroll
        for (int r = 0; r < 6; ++r) {
            const u16* rp = zb + r * P;
            const unsigned u0 = *(const unsigned*)rp;
            const unsigned u1 = *(const unsigned*)(rp + 2);
            float vv[4];
            vv[0] = (float)h2(u0).x; vv[1] = (float)h2(u0).y;
            vv[2] = (float)h2(u1).x; vv[3] = (float)h2(u1).y;
#pragma unroll
            for (int dy = 0; dy < 3; ++dy) {
                const int i = r - dy;
                if (i < 0 || i > 3) continue;  // resolved at compile time
#pragma unroll
                for (int dx = 0; dx < 3; ++dx) {
                    const f32x2 s0 = {vv[dx], vv[dx]};
                    const f32x2 s1 = {vv[dx + 1], vv[dx + 1]};
#pragma unroll
                    for (int j = 0; j < 4; ++j) {
                        const float2 wraw = wz[(dy * 3 + dx) * 4 + j];
                        const f32x2 wv = {wraw.x, wraw.y};
                        acc[i][j][0] = __builtin_elementwise_fma(wv, s0, acc[i][j][0]);
                        acc[i][j][1] = __builtin_elementwise_fma(wv, s1, acc[i][j][1]);
                    }
                }
            }
        }
    }
    const size_t e0 = ((size_t)(d + 1) * P + (h0 + 1)) * P + (w0 + 1);
#pragma unroll
    for (int i = 0; i < 4; ++i) {
        uint4 oA, oB;
        oA.x = pkh_relu(acc[i][0][0].x, acc[i][0][0].y);
        oA.y = pkh_relu(acc[i][1][0].x, acc[i][1][0].y);
        oA.z = pkh_relu(acc[i][2][0].x, acc[i][2][0].y);
        oA.w = pkh_relu(acc[i][3][0].x, acc[i][3][0].y);
        oB.x = pkh_relu(acc[i][0][1].x, acc[i][0][1].y);
        oB.y = pkh_relu(acc[i][1][1].x, acc[i][1][1].y);
        oB.z = pkh_relu(acc[i][2][1].x, acc[i][2][1].y);
        oB.w = pkh_relu(acc[i][3][1].x, acc[i][3][1].y);
        *(uint4*)(x1 + (e0 + (size_t)i * P) * 8) = oA;
        *(uint4*)(x1 + (e0 + (size_t)i * P + 1) * 8) = oB;
    }
}

// conv2: LDS-staged implicit-GEMM MFMA (R8 orientation: A=weights M=16oc,
// B=acts N=16vox). Block = 4 waves = 4 h-rows of one d. Stage the 18 shared
// x1 rows (3dz x 6h = 37.4KB) once; K-loop reads B-frags from LDS with the
// dx shift applied in the LDS address (costless, no epilogue shuffles, no
// extra accumulators). L2-side traffic 448 -> 73 B/voxel.
__global__ __launch_bounds__(256) void conv2_mfma_kernel(
    const u16* __restrict__ x1, const u16* __restrict__ w2frag,
    const float* __restrict__ b2, u16* __restrict__ x2) {
    __shared__ u16 sm[NR * LROW * 8];  // 37440 B

    const int tid = threadIdx.x;
    const int lane = tid & 63;
    const int wv = tid >> 6;  // output h-row offset 0..3
    const int q = lane >> 4;
    const int mi = lane & 15;
    const int d0 = blockIdx.x >> 5;        // 0..127
    const int h0 = (blockIdx.x & 31) * 4;  // 0..124

    // stage rows (d0+dz, h0+r), dz in 0..2, r in 0..5  (2340 uint4)
    for (int u = tid; u < NR * LROW; u += 256) {
        const int row = u / LROW;  // 0..17
        const int pos = u - row * LROW;
        const int dz = row / 6;
        const int r = row - dz * 6;
        const uint4 v = *(const uint4*)(x1 + ((size_t)((d0 + dz) * P + (h0 + r)) * P + pos) * 8);
        *(uint4*)(sm + (size_t)u * 8) = v;
    }

    // weight A-frags (global, wave-uniform pattern -> L1-resident)
    f16x8 wf[7];
#pragma unroll
    for (int s = 0; s < 7; ++s)
        wf[s] = *(const f16x8*)(w2frag + (size_t)(s * 64 + lane) * 8);

    __syncthreads();

    f32x4 acc[8];
#pragma unroll
    for (int t = 0; t < 8; ++t) acc[t] = (f32x4){0.f, 0.f, 0.f, 0.f};

#pragma unroll
    for (int s = 0; s < 7; ++s) {
        int tap = s * 4 + q;
        if (tap > 26) tap = 26;  // pad tap: weight frag is zero there
        const int dz = tap / 9;
        const int rem = tap - dz * 9;
        const int dy = rem / 3;
        const int dx = rem - dy * 3;
        const u16* bp = sm + ((dz * 6 + wv + dy) * LROW + (mi + dx)) * 8;
#pragma unroll
        for (int t = 0; t < 8; ++t) {
            f16x8 act = *(const f16x8*)(bp + t * 128);  // +16 voxels
            acc[t] = __builtin_amdgcn_mfma_f32_16x16x32_f16(wf[s], act, acc[t], 0, 0, 0);
        }
    }

    // D: row(oc)=q*4+r, col(voxel)=mi -> lane stores 4 consecutive channels
    const float4 bv = *(const float4*)(b2 + q * 4);
    const size_t obase = ((size_t)(d0 + 1) * P + (h0 + wv + 1)) * P + 1;
#pragma unroll
    for (int t = 0; t < 8; ++t) {
        uint2 o;
        o.x = pkh_relu(acc[t][0] + bv.x, acc[t][1] + bv.y);
        o.y = pkh_relu(acc[t][2] + bv.z, acc[t][3] + bv.w);
        *(uint2*)(x2 + (obase + 16 * t + mi) * 16 + q * 4) = o;
    }
}

// conv3: padded x2 [130^3][16] f16 -> out fp32 [128^3] (one batch), tanh.
// 2(d) x 8(h) strip per thread; position-major immediate consumption.
__global__ __launch_bounds__(256) void conv3_kernel(
    const u16* __restrict__ x2, const unsigned* __restrict__ w3p,
    const float* __restrict__ b3, float* __restrict__ out) {
    const int t = blockIdx.x * 256 + threadIdx.x;  // VOX/16 threads
    const int w = t & 127;
    const int h0 = ((t >> 7) & 15) * 8;
    const int d0 = (t >> 11) * 2;

    float accA[2][8], accB[2][8];
#pragma unroll
    for (int dd = 0; dd < 2; ++dd)
#pragma unroll
        for (int i = 0; i < 8; ++i) { accA[dd][i] = 0.f; accB[dd][i] = 0.f; }

#pragma unroll 1
    for (int z = 0; z < 4; ++z) {  // padded z-row = d0 + z
        const u16* zb = x2 + ((size_t)((d0 + z) * P + h0) * P + w) * 16;
#pragma unroll
        for (int r = 0; r < 10; ++r) {
            const u16* rp = zb + (size_t)r * (P * 16);
            const uint4 c0l = *(const uint4*)(rp);
            const uint4 c0h = *(const uint4*)(rp + 8);
            const uint4 c1l = *(const uint4*)(rp + 16);
            const uint4 c1h = *(const uint4*)(rp + 24);
            const uint4 c2l = *(const uint4*)(rp + 32);
            const uint4 c2h = *(const uint4*)(rp + 40);
#pragma unroll
            for (int dd = 0; dd < 2; ++dd) {
                const int dz = z - dd;
                if (dz < 0 || dz > 2) continue;  // wave-uniform runtime guard
                const unsigned* wz = w3p + dz * 9 * 8;
#pragma unroll
                for (int dy = 0; dy < 3; ++dy) {
                    const int i = r - dy;
                    if (i < 0 || i > 7) continue;  // compile-time after unroll
                    const unsigned* wp = wz + dy * 3 * 8;
                    float a = accA[dd][i], b = accB[dd][i];
                    a = dot2(c0l.x, wp[0], a);  b = dot2(c0l.y, wp[1], b);
                    a = dot2(c0l.z, wp[2], a);  b = dot2(c0l.w, wp[3], b);
                    a = dot2(c0h.x, wp[4], a);  b = dot2(c0h.y, wp[5], b);
                    a = dot2(c0h.z, wp[6], a);  b = dot2(c0h.w, wp[7], b);
                    a = dot2(c1l.x, wp[8], a);  b = dot2(c1l.y, wp[9], b);
                    a = dot2(c1l.z, wp[10], a); b = dot2(c1l.w, wp[11], b);
                    a = dot2(c1h.x, wp[12], a); b = dot2(c1h.y, wp[13], b);
                    a = dot2(c1h.z, wp[14], a); b = dot2(c1h.w, wp[15], b);
                    a = dot2(c2l.x, wp[16], a); b = dot2(c2l.y, wp[17], b);
                    a = dot2(c2l.z, wp[18], a); b = dot2(c2l.w, wp[19], b);
                    a = dot2(c2h.x, wp[20], a); b = dot2(c2h.y, wp[21], b);
                    a = dot2(c2h.z, wp[22], a); b = dot2(c2h.w, wp[23], b);
                    accA[dd][i] = a; accB[dd][i] = b;
                }
            }
        }
    }
    const float bias = b3[0];
#pragma unroll
    for (int dd = 0; dd < 2; ++dd) {
        const size_t obase = (size_t)((d0 + dd) * 128 + h0) * 128 + w;
#pragma unroll
        for (int i = 0; i < 8; ++i)
            out[obase + (size_t)i * 128] = fast_tanh(accA[dd][i] + accB[dd][i] + bias);
    }
}

extern "C" void kernel_launch(void* const* d_in, const int* in_sizes, int n_in,
                              void* d_out, int out_size, void* d_ws, size_t ws_size,
                              hipStream_t stream) {
    const float* cube = (const float*)d_in[0];
    const float* w1 = (const float*)d_in[1];
    const float* b1 = (const float*)d_in[2];
    const float* w2 = (const float*)d_in[3];
    const float* b2 = (const float*)d_in[4];
    const float* w3 = (const float*)d_in[5];
    const float* b3 = (const float*)d_in[6];
    float* out = (float*)d_out;

    // ws: w2frag@0 (7168B) | w3p@7168 (864B) | w1p@8032 (864B) | x0 @16384 | x1 | x2
    char* ws = (char*)d_ws;
    u16* w2frag = (u16*)ws;
    unsigned* w3p = (unsigned*)(ws + 7168);
    float2* w1p = (float2*)(ws + 8032);
    u16* x0 = (u16*)(ws + 16384);
    u16* x1 = (u16*)(ws + 16384 + (size_t)PVOX * sizeof(u16));
    u16* x2 = (u16*)(ws + 16384 + (size_t)PVOX * sizeof(u16) + (size_t)PVOX * 8 * sizeof(u16));

    setup_kernel<<<dim3((PVOX + 255) / 256), dim3(256), 0, stream>>>(
        w1, w2, w3, w2frag, w3p, w1p, x1, x2);

    for (int b = 0; b < 2; ++b) {
        integrate_kernel<<<dim3((PVOX + 255) / 256), dim3(256), 0, stream>>>(
            cube + (size_t)b * VOX, x0);
        conv1_kernel<<<dim3(VOX / 8 / 256), dim3(256), 0, stream>>>(x0, w1p, b1, x1);
        conv2_mfma_kernel<<<dim3(128 * 32), dim3(256), 0, stream>>>(x1, w2frag, b2, x2);
        conv3_kernel<<<dim3(VOX / 16 / 256), dim3(256), 0, stream>>>(
            x2, w3p, b3, out + (size_t)b * VOX);
    }
}

// Round 11
// 242.847 us; speedup vs baseline: 1.0995x; 1.0277x over previous
//
#include <hip/hip_runtime.h>
#include <hip/hip_fp16.h>

#define VOX (128 * 128 * 128)   // 2097152
#define P 130                   // padded dim
#define PP (P * P)              // 16900
#define PVOX (P * P * P)        // 2197000
#define LROW 130
#define PLANE (6 * LROW)        // rows*pos per dz-plane staged (in 8-u16 units)

typedef unsigned short u16;
typedef _Float16 f16x2 __attribute__((ext_vector_type(2)));
typedef _Float16 f16x8 __attribute__((ext_vector_type(8)));
typedef __attribute__((ext_vector_type(4))) float f32x4;
typedef __attribute__((ext_vector_type(2))) float f32x2;

__device__ __forceinline__ u16 f2h(float f) {
    return __builtin_bit_cast(unsigned short, (_Float16)f);
}
__device__ __forceinline__ unsigned pkh_relu(float a, float b) {
    float ra = a > 0.f ? a : 0.f, rb = b > 0.f ? b : 0.f;
    return (unsigned)f2h(ra) | ((unsigned)f2h(rb) << 16);
}
__device__ __forceinline__ f16x2 h2(unsigned u) { return __builtin_bit_cast(f16x2, u); }

// dot2: acc += a.x*b.x + a.y*b.y  (f32 accumulate, single V_DOT2_F32_F16)
__device__ __forceinline__ float dot2(unsigned a, unsigned b, float c) {
#if __has_builtin(__builtin_amdgcn_fdot2)
    return __builtin_amdgcn_fdot2(h2(a), h2(b), c, false);
#else
    f16x2 av = h2(a), bv = h2(b);
    c = fmaf((float)av.x, (float)bv.x, c);
    return fmaf((float)av.y, (float)bv.y, c);
#endif
}

// fast tanh: 1 - 2/(1+e^{2x})
__device__ __forceinline__ float fast_tanh(float x) {
    float e = __expf(2.0f * x);
    return 1.0f - 2.0f * __builtin_amdgcn_rcpf(1.0f + e);
}

// setup: zero halo shells of x1/x2 + build weight tables (tap-major w2frag).
// w2frag[(s*64+lane)*8+j] = f16(w2[oc=lane&15][ic=j][tap=s*4+(lane>>4)]), 0 if tap>26
// w3p[tap*8+j] = packed f16 pair (w3[2j][tap], w3[2j+1][tap])
// w1p[tap*4+j] = float2 (w1[2j][tap], w1[2j+1][tap])
__global__ __launch_bounds__(256) void setup_kernel(
    const float* __restrict__ w1, const float* __restrict__ w2,
    const float* __restrict__ w3, u16* __restrict__ w2frag,
    unsigned* __restrict__ w3p, float2* __restrict__ w1p,
    u16* __restrict__ x1, u16* __restrict__ x2) {
    int i = blockIdx.x * 256 + threadIdx.x;
    if (i < 3584) {
        int j = i & 7, l = (i >> 3) & 63, s = i >> 9;
        int tap = s * 4 + (l >> 4), oc = l & 15;
        float v = (tap < 27) ? w2[(oc * 8 + j) * 27 + tap] : 0.0f;
        w2frag[i] = f2h(v);
    }
    if (i < 216) {
        int tap = i >> 3, j = i & 7;
        w3p[i] = (unsigned)f2h(w3[(2 * j) * 27 + tap]) |
                 ((unsigned)f2h(w3[(2 * j + 1) * 27 + tap]) << 16);
    }
    if (i < 108) {
        int tap = i >> 2, j = i & 3;
        w1p[i] = make_float2(w1[(2 * j) * 27 + tap], w1[(2 * j + 1) * 27 + tap]);
    }
    if (i >= PVOX) return;
    int d = i / PP;
    int r = i - d * PP;
    int h = r / P;
    int w = r - h * P;
    if (d == 0 || d == P - 1 || h == 0 || h == P - 1 || w == 0 || w == P - 1) {
        uint4 z = {0u, 0u, 0u, 0u};
        *(uint4*)(x1 + (size_t)i * 8) = z;
        *(uint4*)(x2 + (size_t)i * 16) = z;
        *(uint4*)(x2 + (size_t)i * 16 + 8) = z;
    }
}

// integrate: x0 padded f16 [130^3] = cube * (1 + 0.1*sin(2pi*(d+h+w)/384)), halo = 0
__global__ __launch_bounds__(256) void integrate_kernel(
    const float* __restrict__ in, u16* __restrict__ x0) {
    int i = blockIdx.x * 256 + threadIdx.x;
    if (i >= PVOX) return;
    int d = i / PP;
    int r = i - d * PP;
    int h = r / P;
    int w = r - h * P;
    float v = 0.0f;
    if (d >= 1 && d <= 128 && h >= 1 && h <= 128 && w >= 1 && w <= 128) {
        int s = (d - 1) + (h - 1) + (w - 1);
        float fld = 1.0f + 0.1f * sinf(6.283185307179586f * (float)s / 384.0f);
        v = in[(size_t)(d - 1) * 16384 + (h - 1) * 128 + (w - 1)] * fld;
    }
    x0[i] = f2h(v);
}

// conv1: x0 padded f16 [130^3] -> x1 f16 channels-last padded [130^3][8], relu.
// Strip 4(h) x 2(w) voxels/thread; per (dz, r in 0..5): one 4-f16 window load.
__global__ __launch_bounds__(256) void conv1_kernel(
    const u16* __restrict__ x0, const float2* __restrict__ w1p,
    const float* __restrict__ b1, u16* __restrict__ x1) {
    const int t = blockIdx.x * 256 + threadIdx.x;  // VOX/8 threads
    const int w0 = (t & 63) * 2;
    const int h0 = ((t >> 6) & 31) * 4;
    const int d = t >> 11;

    f32x2 acc[4][4][2];  // [i][jpair][vox]
#pragma unroll
    for (int j = 0; j < 4; ++j) {
        const f32x2 b = {b1[2 * j], b1[2 * j + 1]};
#pragma unroll
        for (int i = 0; i < 4; ++i) { acc[i][j][0] = b; acc[i][j][1] = b; }
    }

#pragma unroll
    for (int dz = 0; dz < 3; ++dz) {
        const u16* zb = x0 + (size_t)(d + dz) * PP + (size_t)h0 * P + w0;
        const float2* wz = w1p + dz * 9 * 4;
#pragma unroll
        for (int r = 0; r < 6; ++r) {
            const u16* rp = zb + r * P;
            const unsigned u0 = *(const unsigned*)rp;
            const unsigned u1 = *(const unsigned*)(rp + 2);
            float vv[4];
            vv[0] = (float)h2(u0).x; vv[1] = (float)h2(u0).y;
            vv[2] = (float)h2(u1).x; vv[3] = (float)h2(u1).y;
#pragma unroll
            for (int dy = 0; dy < 3; ++dy) {
                const int i = r - dy;
                if (i < 0 || i > 3) continue;  // resolved at compile time
#pragma unroll
                for (int dx = 0; dx < 3; ++dx) {
                    const f32x2 s0 = {vv[dx], vv[dx]};
                    const f32x2 s1 = {vv[dx + 1], vv[dx + 1]};
#pragma unroll
                    for (int j = 0; j < 4; ++j) {
                        const float2 wraw = wz[(dy * 3 + dx) * 4 + j];
                        const f32x2 wv = {wraw.x, wraw.y};
                        acc[i][j][0] = __builtin_elementwise_fma(wv, s0, acc[i][j][0]);
                        acc[i][j][1] = __builtin_elementwise_fma(wv, s1, acc[i][j][1]);
                    }
                }
            }
        }
    }
    const size_t e0 = ((size_t)(d + 1) * P + (h0 + 1)) * P + (w0 + 1);
#pragma unroll
    for (int i = 0; i < 4; ++i) {
        uint4 oA, oB;
        oA.x = pkh_relu(acc[i][0][0].x, acc[i][0][0].y);
        oA.y = pkh_relu(acc[i][1][0].x, acc[i][1][0].y);
        oA.z = pkh_relu(acc[i][2][0].x, acc[i][2][0].y);
        oA.w = pkh_relu(acc[i][3][0].x, acc[i][3][0].y);
        oB.x = pkh_relu(acc[i][0][1].x, acc[i][0][1].y);
        oB.y = pkh_relu(acc[i][1][1].x, acc[i][1][1].y);
        oB.z = pkh_relu(acc[i][2][1].x, acc[i][2][1].y);
        oB.w = pkh_relu(acc[i][3][1].x, acc[i][3][1].y);
        *(uint4*)(x1 + (e0 + (size_t)i * P) * 8) = oA;
        *(uint4*)(x1 + (e0 + (size_t)i * P + 1) * 8) = oB;
    }
}

// conv2: rolling-d LDS-staged implicit-GEMM MFMA (A=weights M=16oc, B=acts N=16vox).
// Block = 4 waves = 4 h-rows, persistent over a d-chunk of 4. LDS = 4-slot ring
// of dz-planes (6 rows x 130 x 16B = 12.48KB each, 49.9KB total -> 3 blocks/CU).
// Per d-step: prefetch ONE new plane into regs during the 224-MFMA compute,
// then barrier/LDS-write/barrier. Staging 9 rows per output-d (was 18);
// global-load latency overlapped with MFMA instead of serialized.
// Ring invariant: plane pd lives in slot pd&3; the slot overwritten for
// d_out+3 held plane d_out-1, last read two barriers ago.
__global__ __launch_bounds__(256) void conv2_mfma_kernel(
    const u16* __restrict__ x1, const u16* __restrict__ w2frag,
    const float* __restrict__ b2, u16* __restrict__ x2) {
    __shared__ u16 sm[4 * PLANE * 8];  // 49920 B

    const int tid = threadIdx.x;
    const int lane = tid & 63;
    const int wv = tid >> 6;  // output h-row offset 0..3
    const int q = lane >> 4;
    const int mi = lane & 15;
    const int D0 = (blockIdx.x >> 5) * 4;   // d-chunk base (unpadded out d)
    const int h0 = (blockIdx.x & 31) * 4;   // h-tile base

    // weight A-frags (7KB table, L1-resident)
    f16x8 wf[7];
#pragma unroll
    for (int s = 0; s < 7; ++s)
        wf[s] = *(const f16x8*)(w2frag + (size_t)(s * 64 + lane) * 8);

    // stage planes D0, D0+1, D0+2 (padded d index = unpadded out d + dz)
#pragma unroll 1
    for (int p = 0; p < 3; ++p) {
        const int pd = D0 + p;
        const int slot = pd & 3;
        for (int u = tid; u < PLANE; u += 256) {
            const int row = u / LROW;
            const int pos = u - row * LROW;
            const uint4 v = *(const uint4*)(x1 + ((size_t)(pd * P + (h0 + row)) * P + pos) * 8);
            *(uint4*)(sm + ((size_t)(slot * 6 + row) * LROW + pos) * 8) = v;
        }
    }
    __syncthreads();

    const float4 bv = *(const float4*)(b2 + q * 4);

#pragma unroll 1
    for (int i = 0; i < 4; ++i) {
        const int dout = D0 + i;

        // prefetch plane dout+3 into regs (3 uint4 + 1 conditional)
        uint4 pf0, pf1, pf2, pf3;
        const int pdn = dout + 3;
        if (i < 3) {
            {
                const int u = tid, row = u / LROW, pos = u - row * LROW;
                pf0 = *(const uint4*)(x1 + ((size_t)(pdn * P + (h0 + row)) * P + pos) * 8);
            }
            {
                const int u = tid + 256, row = u / LROW, pos = u - row * LROW;
                pf1 = *(const uint4*)(x1 + ((size_t)(pdn * P + (h0 + row)) * P + pos) * 8);
            }
            {
                const int u = tid + 512, row = u / LROW, pos = u - row * LROW;
                pf2 = *(const uint4*)(x1 + ((size_t)(pdn * P + (h0 + row)) * P + pos) * 8);
            }
            if (tid < PLANE - 768) {
                const int u = tid + 768, row = u / LROW, pos = u - row * LROW;
                pf3 = *(const uint4*)(x1 + ((size_t)(pdn * P + (h0 + row)) * P + pos) * 8);
            }
        }

        // compute output plane dout
        f32x4 acc[8];
#pragma unroll
        for (int t = 0; t < 8; ++t) acc[t] = (f32x4){0.f, 0.f, 0.f, 0.f};

#pragma unroll
        for (int s = 0; s < 7; ++s) {
            int tap = s * 4 + q;
            if (tap > 26) tap = 26;  // pad tap: weight frag is zero there
            const int dz = tap / 9;
            const int rem = tap - dz * 9;
            const int dy = rem / 3;
            const int dx = rem - dy * 3;
            const int slot = (dout + dz) & 3;
            const u16* bp = sm + ((size_t)(slot * 6 + wv + dy) * LROW + (mi + dx)) * 8;
#pragma unroll
            for (int t = 0; t < 8; ++t) {
                f16x8 act = *(const f16x8*)(bp + t * 128);  // +16 voxels
                acc[t] = __builtin_amdgcn_mfma_f32_16x16x32_f16(wf[s], act, acc[t], 0, 0, 0);
            }
        }

        // D: row(oc)=q*4+r, col(voxel)=mi -> lane stores 4 consecutive channels
        const size_t obase = ((size_t)(dout + 1) * P + (h0 + wv + 1)) * P + 1;
#pragma unroll
        for (int t = 0; t < 8; ++t) {
            uint2 o;
            o.x = pkh_relu(acc[t][0] + bv.x, acc[t][1] + bv.y);
            o.y = pkh_relu(acc[t][2] + bv.z, acc[t][3] + bv.w);
            *(uint2*)(x2 + (obase + 16 * t + mi) * 16 + q * 4) = o;
        }

        // rotate ring: write prefetched plane
        if (i < 3) {
            __syncthreads();
            const int slot = pdn & 3;
            {
                const int u = tid, row = u / LROW, pos = u - row * LROW;
                *(uint4*)(sm + ((size_t)(slot * 6 + row) * LROW + pos) * 8) = pf0;
            }
            {
                const int u = tid + 256, row = u / LROW, pos = u - row * LROW;
                *(uint4*)(sm + ((size_t)(slot * 6 + row) * LROW + pos) * 8) = pf1;
            }
            {
                const int u = tid + 512, row = u / LROW, pos = u - row * LROW;
                *(uint4*)(sm + ((size_t)(slot * 6 + row) * LROW + pos) * 8) = pf2;
            }
            if (tid < PLANE - 768) {
                const int u = tid + 768, row = u / LROW, pos = u - row * LROW;
                *(uint4*)(sm + ((size_t)(slot * 6 + row) * LROW + pos) * 8) = pf3;
            }
            __syncthreads();
        }
    }
}

// conv3: padded x2 [130^3][16] f16 -> out fp32 [128^3] (one batch), tanh.
// 2(d) x 8(h) strip per thread; position-major immediate consumption.
__global__ __launch_bounds__(256) void conv3_kernel(
    const u16* __restrict__ x2, const unsigned* __restrict__ w3p,
    const float* __restrict__ b3, float* __restrict__ out) {
    const int t = blockIdx.x * 256 + threadIdx.x;  // VOX/16 threads
    const int w = t & 127;
    const int h0 = ((t >> 7) & 15) * 8;
    const int d0 = (t >> 11) * 2;

    float accA[2][8], accB[2][8];
#pragma unroll
    for (int dd = 0; dd < 2; ++dd)
#pragma unroll
        for (int i = 0; i < 8; ++i) { accA[dd][i] = 0.f; accB[dd][i] = 0.f; }

#pragma unroll 1
    for (int z = 0; z < 4; ++z) {  // padded z-row = d0 + z
        const u16* zb = x2 + ((size_t)((d0 + z) * P + h0) * P + w) * 16;
#pragma unroll
        for (int r = 0; r < 10; ++r) {
            const u16* rp = zb + (size_t)r * (P * 16);
            const uint4 c0l = *(const uint4*)(rp);
            const uint4 c0h = *(const uint4*)(rp + 8);
            const uint4 c1l = *(const uint4*)(rp + 16);
            const uint4 c1h = *(const uint4*)(rp + 24);
            const uint4 c2l = *(const uint4*)(rp + 32);
            const uint4 c2h = *(const uint4*)(rp + 40);
#pragma unroll
            for (int dd = 0; dd < 2; ++dd) {
                const int dz = z - dd;
                if (dz < 0 || dz > 2) continue;  // wave-uniform runtime guard
                const unsigned* wz = w3p + dz * 9 * 8;
#pragma unroll
                for (int dy = 0; dy < 3; ++dy) {
                    const int i = r - dy;
                    if (i < 0 || i > 7) continue;  // compile-time after unroll
                    const unsigned* wp = wz + dy * 3 * 8;
                    float a = accA[dd][i], b = accB[dd][i];
                    a = dot2(c0l.x, wp[0], a);  b = dot2(c0l.y, wp[1], b);
                    a = dot2(c0l.z, wp[2], a);  b = dot2(c0l.w, wp[3], b);
                    a = dot2(c0h.x, wp[4], a);  b = dot2(c0h.y, wp[5], b);
                    a = dot2(c0h.z, wp[6], a);  b = dot2(c0h.w, wp[7], b);
                    a = dot2(c1l.x, wp[8], a);  b = dot2(c1l.y, wp[9], b);
                    a = dot2(c1l.z, wp[10], a); b = dot2(c1l.w, wp[11], b);
                    a = dot2(c1h.x, wp[12], a); b = dot2(c1h.y, wp[13], b);
                    a = dot2(c1h.z, wp[14], a); b = dot2(c1h.w, wp[15], b);
                    a = dot2(c2l.x, wp[16], a); b = dot2(c2l.y, wp[17], b);
                    a = dot2(c2l.z, wp[18], a); b = dot2(c2l.w, wp[19], b);
                    a = dot2(c2h.x, wp[20], a); b = dot2(c2h.y, wp[21], b);
                    a = dot2(c2h.z, wp[22], a); b = dot2(c2h.w, wp[23], b);
                    accA[dd][i] = a; accB[dd][i] = b;
                }
            }
        }
    }
    const float bias = b3[0];
#pragma unroll
    for (int dd = 0; dd < 2; ++dd) {
        const size_t obase = (size_t)((d0 + dd) * 128 + h0) * 128 + w;
#pragma unroll
        for (int i = 0; i < 8; ++i)
            out[obase + (size_t)i * 128] = fast_tanh(accA[dd][i] + accB[dd][i] + bias);
    }
}

extern "C" void kernel_launch(void* const* d_in, const int* in_sizes, int n_in,
                              void* d_out, int out_size, void* d_ws, size_t ws_size,
                              hipStream_t stream) {
    const float* cube = (const float*)d_in[0];
    const float* w1 = (const float*)d_in[1];
    const float* b1 = (const float*)d_in[2];
    const float* w2 = (const float*)d_in[3];
    const float* b2 = (const float*)d_in[4];
    const float* w3 = (const float*)d_in[5];
    const float* b3 = (const float*)d_in[6];
    float* out = (float*)d_out;

    // ws: w2frag@0 (7168B) | w3p@7168 (864B) | w1p@8032 (864B) | x0 @16384 | x1 | x2
    char* ws = (char*)d_ws;
    u16* w2frag = (u16*)ws;
    unsigned* w3p = (unsigned*)(ws + 7168);
    float2* w1p = (float2*)(ws + 8032);
    u16* x0 = (u16*)(ws + 16384);
    u16* x1 = (u16*)(ws + 16384 + (size_t)PVOX * sizeof(u16));
    u16* x2 = (u16*)(ws + 16384 + (size_t)PVOX * sizeof(u16) + (size_t)PVOX * 8 * sizeof(u16));

    setup_kernel<<<dim3((PVOX + 255) / 256), dim3(256), 0, stream>>>(
        w1, w2, w3, w2frag, w3p, w1p, x1, x2);

    for (int b = 0; b < 2; ++b) {
        integrate_kernel<<<dim3((PVOX + 255) / 256), dim3(256), 0, stream>>>(
            cube + (size_t)b * VOX, x0);
        conv1_kernel<<<dim3(VOX / 8 / 256), dim3(256), 0, stream>>>(x0, w1p, b1, x1);
        conv2_mfma_kernel<<<dim3(1024), dim3(256), 0, stream>>>(x1, w2frag, b2, x2);
        conv3_kernel<<<dim3(VOX / 16 / 256), dim3(256), 0, stream>>>(
            x2, w3p, b3, out + (size_t)b * VOX);
    }
}

// Round 12
// 227.745 us; speedup vs baseline: 1.1725x; 1.0663x over previous
//
#include <hip/hip_runtime.h>
#include <hip/hip_fp16.h>

#define VOX (128 * 128 * 128)   // 2097152
#define P 130                   // padded dim
#define PP (P * P)              // 16900
#define PVOX (P * P * P)        // 2197000
#define LROW 130
#define PLANE (6 * LROW)        // 780 16B-units per staged dz-plane

typedef unsigned short u16;
typedef _Float16 f16x2 __attribute__((ext_vector_type(2)));
typedef _Float16 f16x8 __attribute__((ext_vector_type(8)));
typedef __attribute__((ext_vector_type(4))) float f32x4;
typedef __attribute__((ext_vector_type(2))) float f32x2;

__device__ __forceinline__ u16 f2h(float f) {
    return __builtin_bit_cast(unsigned short, (_Float16)f);
}
__device__ __forceinline__ unsigned pkh_relu(float a, float b) {
    float ra = a > 0.f ? a : 0.f, rb = b > 0.f ? b : 0.f;
    return (unsigned)f2h(ra) | ((unsigned)f2h(rb) << 16);
}
__device__ __forceinline__ f16x2 h2(unsigned u) { return __builtin_bit_cast(f16x2, u); }

// dot2: acc += a.x*b.x + a.y*b.y  (f32 accumulate, single V_DOT2_F32_F16)
__device__ __forceinline__ float dot2(unsigned a, unsigned b, float c) {
#if __has_builtin(__builtin_amdgcn_fdot2)
    return __builtin_amdgcn_fdot2(h2(a), h2(b), c, false);
#else
    f16x2 av = h2(a), bv = h2(b);
    c = fmaf((float)av.x, (float)bv.x, c);
    return fmaf((float)av.y, (float)bv.y, c);
#endif
}

// fast tanh: 1 - 2/(1+e^{2x})
__device__ __forceinline__ float fast_tanh(float x) {
    float e = __expf(2.0f * x);
    return 1.0f - 2.0f * __builtin_amdgcn_rcpf(1.0f + e);
}

// async global->LDS DMA, 16B per lane. LDS dest = wave-uniform base + lane*16.
__device__ __forceinline__ void gload_lds16(const u16* g, u16* l) {
    __builtin_amdgcn_global_load_lds(
        (const __attribute__((address_space(1))) unsigned int*)g,
        (__attribute__((address_space(3))) unsigned int*)l,
        16, 0, 0);
}

// setup: zero halo shells of x1/x2 + build weight tables (tap-major w2frag).
// w2frag[(s*64+lane)*8+j] = f16(w2[oc=lane&15][ic=j][tap=s*4+(lane>>4)]), 0 if tap>26
// w3p[tap*8+j] = packed f16 pair (w3[2j][tap], w3[2j+1][tap])
// w1p[tap*4+j] = float2 (w1[2j][tap], w1[2j+1][tap])
__global__ __launch_bounds__(256) void setup_kernel(
    const float* __restrict__ w1, const float* __restrict__ w2,
    const float* __restrict__ w3, u16* __restrict__ w2frag,
    unsigned* __restrict__ w3p, float2* __restrict__ w1p,
    u16* __restrict__ x1, u16* __restrict__ x2) {
    int i = blockIdx.x * 256 + threadIdx.x;
    if (i < 3584) {
        int j = i & 7, l = (i >> 3) & 63, s = i >> 9;
        int tap = s * 4 + (l >> 4), oc = l & 15;
        float v = (tap < 27) ? w2[(oc * 8 + j) * 27 + tap] : 0.0f;
        w2frag[i] = f2h(v);
    }
    if (i < 216) {
        int tap = i >> 3, j = i & 7;
        w3p[i] = (unsigned)f2h(w3[(2 * j) * 27 + tap]) |
                 ((unsigned)f2h(w3[(2 * j + 1) * 27 + tap]) << 16);
    }
    if (i < 108) {
        int tap = i >> 2, j = i & 3;
        w1p[i] = make_float2(w1[(2 * j) * 27 + tap], w1[(2 * j + 1) * 27 + tap]);
    }
    if (i >= PVOX) return;
    int d = i / PP;
    int r = i - d * PP;
    int h = r / P;
    int w = r - h * P;
    if (d == 0 || d == P - 1 || h == 0 || h == P - 1 || w == 0 || w == P - 1) {
        uint4 z = {0u, 0u, 0u, 0u};
        *(uint4*)(x1 + (size_t)i * 8) = z;
        *(uint4*)(x2 + (size_t)i * 16) = z;
        *(uint4*)(x2 + (size_t)i * 16 + 8) = z;
    }
}

// integrate: x0 padded f16 [130^3] = cube * (1 + 0.1*sin(2pi*(d+h+w)/384)), halo = 0
__global__ __launch_bounds__(256) void integrate_kernel(
    const float* __restrict__ in, u16* __restrict__ x0) {
    int i = blockIdx.x * 256 + threadIdx.x;
    if (i >= PVOX) return;
    int d = i / PP;
    int r = i - d * PP;
    int h = r / P;
    int w = r - h * P;
    float v = 0.0f;
    if (d >= 1 && d <= 128 && h >= 1 && h <= 128 && w >= 1 && w <= 128) {
        int s = (d - 1) + (h - 1) + (w - 1);
        float fld = 1.0f + 0.1f * sinf(6.283185307179586f * (float)s / 384.0f);
        v = in[(size_t)(d - 1) * 16384 + (h - 1) * 128 + (w - 1)] * fld;
    }
    x0[i] = f2h(v);
}

// conv1: x0 padded f16 [130^3] -> x1 f16 channels-last padded [130^3][8], relu.
// Strip 4(h) x 2(w) voxels/thread; per (dz, r in 0..5): one 4-f16 window load.
__global__ __launch_bounds__(256) void conv1_kernel(
    const u16* __restrict__ x0, const float2* __restrict__ w1p,
    const float* __restrict__ b1, u16* __restrict__ x1) {
    const int t = blockIdx.x * 256 + threadIdx.x;  // VOX/8 threads
    const int w0 = (t & 63) * 2;
    const int h0 = ((t >> 6) & 31) * 4;
    const int d = t >> 11;

    f32x2 acc[4][4][2];  // [i][jpair][vox]
#pragma unroll
    for (int j = 0; j < 4; ++j) {
        const f32x2 b = {b1[2 * j], b1[2 * j + 1]};
#pragma unroll
        for (int i = 0; i < 4; ++i) { acc[i][j][0] = b; acc[i][j][1] = b; }
    }

#pragma unroll
    for (int dz = 0; dz < 3; ++dz) {
        const u16* zb = x0 + (size_t)(d + dz) * PP + (size_t)h0 * P + w0;
        const float2* wz = w1p + dz * 9 * 4;
#pragma unroll
        for (int r = 0; r < 6; ++r) {
            const u16* rp = zb + r * P;
            const unsigned u0 = *(const unsigned*)rp;
            const unsigned u1 = *(const unsigned*)(rp + 2);
            float vv[4];
            vv[0] = (float)h2(u0).x; vv[1] = (float)h2(u0).y;
            vv[2] = (float)h2(u1).x; vv[3] = (float)h2(u1).y;
#pragma unroll
            for (int dy = 0; dy < 3; ++dy) {
                const int i = r - dy;
                if (i < 0 || i > 3) continue;  // resolved at compile time
#pragma unroll
                for (int dx = 0; dx < 3; ++dx) {
                    const f32x2 s0 = {vv[dx], vv[dx]};
                    const f32x2 s1 = {vv[dx + 1], vv[dx + 1]};
#pragma unroll
                    for (int j = 0; j < 4; ++j) {
                        const float2 wraw = wz[(dy * 3 + dx) * 4 + j];
                        const f32x2 wv = {wraw.x, wraw.y};
                        acc[i][j][0] = __builtin_elementwise_fma(wv, s0, acc[i][j][0]);
                        acc[i][j][1] = __builtin_elementwise_fma(wv, s1, acc[i][j][1]);
                    }
                }
            }
        }
    }
    const size_t e0 = ((size_t)(d + 1) * P + (h0 + 1)) * P + (w0 + 1);
#pragma unroll
    for (int i = 0; i < 4; ++i) {
        uint4 oA, oB;
        oA.x = pkh_relu(acc[i][0][0].x, acc[i][0][0].y);
        oA.y = pkh_relu(acc[i][1][0].x, acc[i][1][0].y);
        oA.z = pkh_relu(acc[i][2][0].x, acc[i][2][0].y);
        oA.w = pkh_relu(acc[i][3][0].x, acc[i][3][0].y);
        oB.x = pkh_relu(acc[i][0][1].x, acc[i][0][1].y);
        oB.y = pkh_relu(acc[i][1][1].x, acc[i][1][1].y);
        oB.z = pkh_relu(acc[i][2][1].x, acc[i][2][1].y);
        oB.w = pkh_relu(acc[i][3][1].x, acc[i][3][1].y);
        *(uint4*)(x1 + (e0 + (size_t)i * P) * 8) = oA;
        *(uint4*)(x1 + (e0 + (size_t)i * P + 1) * 8) = oB;
    }
}

// conv2: rolling-d LDS-staged implicit-GEMM MFMA, ASYNC staging via
// global_load_lds (16B). Key: LROW==P==130 makes the plane copy perfectly
// linear (global off = base + u*16, LDS off = base + u*16), matching the
// wave-uniform-base + lane*16 DMA contract. One barrier per d-step: the DMA
// target slot ((dout+3)&3 == (dout-1)&3) is not read by this step's compute,
// and __syncthreads' implicit vmcnt(0) drains each wave's own DMAs.
__global__ __launch_bounds__(256) void conv2_mfma_kernel(
    const u16* __restrict__ x1, const u16* __restrict__ w2frag,
    const float* __restrict__ b2, u16* __restrict__ x2) {
    __shared__ u16 sm[4 * PLANE * 8];  // 49920 B -> 3 blocks/CU

    const int tid = threadIdx.x;
    const int lane = tid & 63;
    const int wv = tid >> 6;  // output h-row offset 0..3
    const int q = lane >> 4;
    const int mi = lane & 15;
    const int D0 = (blockIdx.x >> 5) * 4;   // d-chunk base (unpadded out d)
    const int h0 = (blockIdx.x & 31) * 4;   // h-tile base

    // weight A-frags (7KB table, L1-resident)
    f16x8 wf[7];
#pragma unroll
    for (int s = 0; s < 7; ++s)
        wf[s] = *(const f16x8*)(w2frag + (size_t)(s * 64 + lane) * 8);

    // async stage planes D0..D0+2 (padded plane index pd covers rows h0..h0+5)
#pragma unroll
    for (int p = 0; p < 3; ++p) {
        const int pd = D0 + p;
        const int slot = pd & 3;
        const u16* gb = x1 + ((size_t)(pd * P + h0) * P) * 8;
        u16* lb = sm + (size_t)slot * PLANE * 8;
#pragma unroll
        for (int k = 0; k < 3; ++k) {
            const int u0 = wv * 64 + k * 256;
            gload_lds16(gb + (size_t)(u0 + lane) * 8, lb + (size_t)u0 * 8);
        }
        if (wv == 0 && lane < PLANE - 768)
            gload_lds16(gb + (size_t)(768 + lane) * 8, lb + (size_t)768 * 8);
    }
    __syncthreads();

    const float4 bv = *(const float4*)(b2 + q * 4);

#pragma unroll 1
    for (int i = 0; i < 4; ++i) {
        const int dout = D0 + i;

        // async prefetch plane dout+3 into its ring slot (unread this step)
        if (i < 3) {
            const int pd = dout + 3;
            const int slot = pd & 3;
            const u16* gb = x1 + ((size_t)(pd * P + h0) * P) * 8;
            u16* lb = sm + (size_t)slot * PLANE * 8;
#pragma unroll
            for (int k = 0; k < 3; ++k) {
                const int u0 = wv * 64 + k * 256;
                gload_lds16(gb + (size_t)(u0 + lane) * 8, lb + (size_t)u0 * 8);
            }
            if (wv == 0 && lane < PLANE - 768)
                gload_lds16(gb + (size_t)(768 + lane) * 8, lb + (size_t)768 * 8);
        }

        // compute output plane dout from slots (dout..dout+2)&3
        f32x4 acc[8];
#pragma unroll
        for (int t = 0; t < 8; ++t) acc[t] = (f32x4){0.f, 0.f, 0.f, 0.f};

#pragma unroll
        for (int s = 0; s < 7; ++s) {
            int tap = s * 4 + q;
            if (tap > 26) tap = 26;  // pad tap: weight frag is zero there
            const int dz = tap / 9;
            const int rem = tap - dz * 9;
            const int dy = rem / 3;
            const int dx = rem - dy * 3;
            const int slot = (dout + dz) & 3;
            const u16* bp = sm + ((size_t)(slot * 6 + wv + dy) * LROW + (mi + dx)) * 8;
#pragma unroll
            for (int t = 0; t < 8; ++t) {
                f16x8 act = *(const f16x8*)(bp + t * 128);  // +16 voxels
                acc[t] = __builtin_amdgcn_mfma_f32_16x16x32_f16(wf[s], act, acc[t], 0, 0, 0);
            }
        }

        // D: row(oc)=q*4+r, col(voxel)=mi -> lane stores 4 consecutive channels
        const size_t obase = ((size_t)(dout + 1) * P + (h0 + wv + 1)) * P + 1;
#pragma unroll
        for (int t = 0; t < 8; ++t) {
            uint2 o;
            o.x = pkh_relu(acc[t][0] + bv.x, acc[t][1] + bv.y);
            o.y = pkh_relu(acc[t][2] + bv.z, acc[t][3] + bv.w);
            *(uint2*)(x2 + (obase + 16 * t + mi) * 16 + q * 4) = o;
        }

        if (i < 3) __syncthreads();  // drains own DMAs (vmcnt) + publishes plane
    }
}

// conv3: padded x2 [130^3][16] f16 -> out fp32 [128^3] (one batch), tanh.
// 2(d) x 8(h) strip per thread; position-major immediate consumption.
__global__ __launch_bounds__(256) void conv3_kernel(
    const u16* __restrict__ x2, const unsigned* __restrict__ w3p,
    const float* __restrict__ b3, float* __restrict__ out) {
    const int t = blockIdx.x * 256 + threadIdx.x;  // VOX/16 threads
    const int w = t & 127;
    const int h0 = ((t >> 7) & 15) * 8;
    const int d0 = (t >> 11) * 2;

    float accA[2][8], accB[2][8];
#pragma unroll
    for (int dd = 0; dd < 2; ++dd)
#pragma unroll
        for (int i = 0; i < 8; ++i) { accA[dd][i] = 0.f; accB[dd][i] = 0.f; }

#pragma unroll 1
    for (int z = 0; z < 4; ++z) {  // padded z-row = d0 + z
        const u16* zb = x2 + ((size_t)((d0 + z) * P + h0) * P + w) * 16;
#pragma unroll
        for (int r = 0; r < 10; ++r) {
            const u16* rp = zb + (size_t)r * (P * 16);
            const uint4 c0l = *(const uint4*)(rp);
            const uint4 c0h = *(const uint4*)(rp + 8);
            const uint4 c1l = *(const uint4*)(rp + 16);
            const uint4 c1h = *(const uint4*)(rp + 24);
            const uint4 c2l = *(const uint4*)(rp + 32);
            const uint4 c2h = *(const uint4*)(rp + 40);
#pragma unroll
            for (int dd = 0; dd < 2; ++dd) {
                const int dz = z - dd;
                if (dz < 0 || dz > 2) continue;  // wave-uniform runtime guard
                const unsigned* wz = w3p + dz * 9 * 8;
#pragma unroll
                for (int dy = 0; dy < 3; ++dy) {
                    const int i = r - dy;
                    if (i < 0 || i > 7) continue;  // compile-time after unroll
                    const unsigned* wp = wz + dy * 3 * 8;
                    float a = accA[dd][i], b = accB[dd][i];
                    a = dot2(c0l.x, wp[0], a);  b = dot2(c0l.y, wp[1], b);
                    a = dot2(c0l.z, wp[2], a);  b = dot2(c0l.w, wp[3], b);
                    a = dot2(c0h.x, wp[4], a);  b = dot2(c0h.y, wp[5], b);
                    a = dot2(c0h.z, wp[6], a);  b = dot2(c0h.w, wp[7], b);
                    a = dot2(c1l.x, wp[8], a);  b = dot2(c1l.y, wp[9], b);
                    a = dot2(c1l.z, wp[10], a); b = dot2(c1l.w, wp[11], b);
                    a = dot2(c1h.x, wp[12], a); b = dot2(c1h.y, wp[13], b);
                    a = dot2(c1h.z, wp[14], a); b = dot2(c1h.w, wp[15], b);
                    a = dot2(c2l.x, wp[16], a); b = dot2(c2l.y, wp[17], b);
                    a = dot2(c2l.z, wp[18], a); b = dot2(c2l.w, wp[19], b);
                    a = dot2(c2h.x, wp[20], a); b = dot2(c2h.y, wp[21], b);
                    a = dot2(c2h.z, wp[22], a); b = dot2(c2h.w, wp[23], b);
                    accA[dd][i] = a; accB[dd][i] = b;
                }
            }
        }
    }
    const float bias = b3[0];
#pragma unroll
    for (int dd = 0; dd < 2; ++dd) {
        const size_t obase = (size_t)((d0 + dd) * 128 + h0) * 128 + w;
#pragma unroll
        for (int i = 0; i < 8; ++i)
            out[obase + (size_t)i * 128] = fast_tanh(accA[dd][i] + accB[dd][i] + bias);
    }
}

extern "C" void kernel_launch(void* const* d_in, const int* in_sizes, int n_in,
                              void* d_out, int out_size, void* d_ws, size_t ws_size,
                              hipStream_t stream) {
    const float* cube = (const float*)d_in[0];
    const float* w1 = (const float*)d_in[1];
    const float* b1 = (const float*)d_in[2];
    const float* w2 = (const float*)d_in[3];
    const float* b2 = (const float*)d_in[4];
    const float* w3 = (const float*)d_in[5];
    const float* b3 = (const float*)d_in[6];
    float* out = (float*)d_out;

    // ws: w2frag@0 (7168B) | w3p@7168 (864B) | w1p@8032 (864B) | x0 @16384 | x1 | x2
    char* ws = (char*)d_ws;
    u16* w2frag = (u16*)ws;
    unsigned* w3p = (unsigned*)(ws + 7168);
    float2* w1p = (float2*)(ws + 8032);
    u16* x0 = (u16*)(ws + 16384);
    u16* x1 = (u16*)(ws + 16384 + (size_t)PVOX * sizeof(u16));
    u16* x2 = (u16*)(ws + 16384 + (size_t)PVOX * sizeof(u16) + (size_t)PVOX * 8 * sizeof(u16));

    setup_kernel<<<dim3((PVOX + 255) / 256), dim3(256), 0, stream>>>(
        w1, w2, w3, w2frag, w3p, w1p, x1, x2);

    for (int b = 0; b < 2; ++b) {
        integrate_kernel<<<dim3((PVOX + 255) / 256), dim3(256), 0, stream>>>(
            cube + (size_t)b * VOX, x0);
        conv1_kernel<<<dim3(VOX / 8 / 256), dim3(256), 0, stream>>>(x0, w1p, b1, x1);
        conv2_mfma_kernel<<<dim3(1024), dim3(256), 0, stream>>>(x1, w2frag, b2, x2);
        conv3_kernel<<<dim3(VOX / 16 / 256), dim3(256), 0, stream>>>(
            x2, w3p, b3, out + (size_t)b * VOX);
    }
}

// Round 13
// 218.049 us; speedup vs baseline: 1.2246x; 1.0445x over previous
//
#include <hip/hip_runtime.h>
#include <hip/hip_fp16.h>

#define VOX (128 * 128 * 128)   // 2097152
#define P 130                   // padded dim
#define PP (P * P)              // 16900
#define PVOX (P * P * P)        // 2197000
#define LROW 130
#define PLANE (6 * LROW)        // 780 16B-units per staged dz-plane

typedef unsigned short u16;
typedef _Float16 f16x2 __attribute__((ext_vector_type(2)));
typedef _Float16 f16x8 __attribute__((ext_vector_type(8)));
typedef __attribute__((ext_vector_type(4))) float f32x4;
typedef __attribute__((ext_vector_type(2))) float f32x2;

__device__ __forceinline__ u16 f2h(float f) {
    return __builtin_bit_cast(unsigned short, (_Float16)f);
}
__device__ __forceinline__ unsigned pkh_relu(float a, float b) {
    float ra = a > 0.f ? a : 0.f, rb = b > 0.f ? b : 0.f;
    return (unsigned)f2h(ra) | ((unsigned)f2h(rb) << 16);
}
__device__ __forceinline__ f16x2 h2(unsigned u) { return __builtin_bit_cast(f16x2, u); }

// dot2: acc += a.x*b.x + a.y*b.y  (f32 accumulate, single V_DOT2_F32_F16)
__device__ __forceinline__ float dot2(unsigned a, unsigned b, float c) {
#if __has_builtin(__builtin_amdgcn_fdot2)
    return __builtin_amdgcn_fdot2(h2(a), h2(b), c, false);
#else
    f16x2 av = h2(a), bv = h2(b);
    c = fmaf((float)av.x, (float)bv.x, c);
    return fmaf((float)av.y, (float)bv.y, c);
#endif
}

// fast tanh: 1 - 2/(1+e^{2x})
__device__ __forceinline__ float fast_tanh(float x) {
    float e = __expf(2.0f * x);
    return 1.0f - 2.0f * __builtin_amdgcn_rcpf(1.0f + e);
}

// async global->LDS DMA, 16B per lane. LDS dest = wave-uniform base + lane*16.
__device__ __forceinline__ void gload_lds16(const u16* g, u16* l) {
    __builtin_amdgcn_global_load_lds(
        (const __attribute__((address_space(1))) unsigned int*)g,
        (__attribute__((address_space(3))) unsigned int*)l,
        16, 0, 0);
}

// integrate + setup (merged; idempotent across batches):
//  x0 padded f16 [130^3] = cube * (1 + 0.1*sin(2pi*(d+h+w)/384)), halo = 0
//  zero halo shells of x1 (8ch) / x2 (16ch)
//  w2frag[(s*64+lane)*8+j] = f16(w2[oc=lane&15][ic=j][tap=s*4+(lane>>4)]), 0 if tap>26
//  w3p[tap*8+j] = packed f16 pair (w3[2j][tap], w3[2j+1][tap])
//  w1p[tap*4+j] = float2 (w1[2j][tap], w1[2j+1][tap])
__global__ __launch_bounds__(256) void integrate_kernel(
    const float* __restrict__ in, u16* __restrict__ x0,
    const float* __restrict__ w1, const float* __restrict__ w2,
    const float* __restrict__ w3, u16* __restrict__ w2frag,
    unsigned* __restrict__ w3p, float2* __restrict__ w1p,
    u16* __restrict__ x1, u16* __restrict__ x2) {
    int i = blockIdx.x * 256 + threadIdx.x;
    if (i < 3584) {
        int j = i & 7, l = (i >> 3) & 63, s = i >> 9;
        int tap = s * 4 + (l >> 4), oc = l & 15;
        float v = (tap < 27) ? w2[(oc * 8 + j) * 27 + tap] : 0.0f;
        w2frag[i] = f2h(v);
    }
    if (i < 216) {
        int tap = i >> 3, j = i & 7;
        w3p[i] = (unsigned)f2h(w3[(2 * j) * 27 + tap]) |
                 ((unsigned)f2h(w3[(2 * j + 1) * 27 + tap]) << 16);
    }
    if (i < 108) {
        int tap = i >> 2, j = i & 3;
        w1p[i] = make_float2(w1[(2 * j) * 27 + tap], w1[(2 * j + 1) * 27 + tap]);
    }
    if (i >= PVOX) return;
    int d = i / PP;
    int r = i - d * PP;
    int h = r / P;
    int w = r - h * P;
    const bool interior = (d >= 1 && d <= 128 && h >= 1 && h <= 128 && w >= 1 && w <= 128);
    float v = 0.0f;
    if (interior) {
        int s = (d - 1) + (h - 1) + (w - 1);
        float fld = 1.0f + 0.1f * sinf(6.283185307179586f * (float)s / 384.0f);
        v = in[(size_t)(d - 1) * 16384 + (h - 1) * 128 + (w - 1)] * fld;
    } else {
        uint4 z = {0u, 0u, 0u, 0u};
        *(uint4*)(x1 + (size_t)i * 8) = z;
        *(uint4*)(x2 + (size_t)i * 16) = z;
        *(uint4*)(x2 + (size_t)i * 16 + 8) = z;
    }
    x0[i] = f2h(v);
}

// conv1: x0 padded f16 [130^3] -> x1 f16 channels-last padded [130^3][8], relu.
// Strip 4(h) x 2(w) voxels/thread; per (dz, r in 0..5): one 4-f16 window load.
__global__ __launch_bounds__(256) void conv1_kernel(
    const u16* __restrict__ x0, const float2* __restrict__ w1p,
    const float* __restrict__ b1, u16* __restrict__ x1) {
    const int t = blockIdx.x * 256 + threadIdx.x;  // VOX/8 threads
    const int w0 = (t & 63) * 2;
    const int h0 = ((t >> 6) & 31) * 4;
    const int d = t >> 11;

    f32x2 acc[4][4][2];  // [i][jpair][vox]
#pragma unroll
    for (int j = 0; j < 4; ++j) {
        const f32x2 b = {b1[2 * j], b1[2 * j + 1]};
#pragma unroll
        for (int i = 0; i < 4; ++i) { acc[i][j][0] = b; acc[i][j][1] = b; }
    }

#pragma unroll
    for (int dz = 0; dz < 3; ++dz) {
        const u16* zb = x0 + (size_t)(d + dz) * PP + (size_t)h0 * P + w0;
        const float2* wz = w1p + dz * 9 * 4;
#pragma unroll
        for (int r = 0; r < 6; ++r) {
            const u16* rp = zb + r * P;
            const unsigned u0 = *(const unsigned*)rp;
            const unsigned u1 = *(const unsigned*)(rp + 2);
            float vv[4];
            vv[0] = (float)h2(u0).x; vv[1] = (float)h2(u0).y;
            vv[2] = (float)h2(u1).x; vv[3] = (float)h2(u1).y;
#pragma unroll
            for (int dy = 0; dy < 3; ++dy) {
                const int i = r - dy;
                if (i < 0 || i > 3) continue;  // resolved at compile time
#pragma unroll
                for (int dx = 0; dx < 3; ++dx) {
                    const f32x2 s0 = {vv[dx], vv[dx]};
                    const f32x2 s1 = {vv[dx + 1], vv[dx + 1]};
#pragma unroll
                    for (int j = 0; j < 4; ++j) {
                        const float2 wraw = wz[(dy * 3 + dx) * 4 + j];
                        const f32x2 wv = {wraw.x, wraw.y};
                        acc[i][j][0] = __builtin_elementwise_fma(wv, s0, acc[i][j][0]);
                        acc[i][j][1] = __builtin_elementwise_fma(wv, s1, acc[i][j][1]);
                    }
                }
            }
        }
    }
    const size_t e0 = ((size_t)(d + 1) * P + (h0 + 1)) * P + (w0 + 1);
#pragma unroll
    for (int i = 0; i < 4; ++i) {
        uint4 oA, oB;
        oA.x = pkh_relu(acc[i][0][0].x, acc[i][0][0].y);
        oA.y = pkh_relu(acc[i][1][0].x, acc[i][1][0].y);
        oA.z = pkh_relu(acc[i][2][0].x, acc[i][2][0].y);
        oA.w = pkh_relu(acc[i][3][0].x, acc[i][3][0].y);
        oB.x = pkh_relu(acc[i][0][1].x, acc[i][0][1].y);
        oB.y = pkh_relu(acc[i][1][1].x, acc[i][1][1].y);
        oB.z = pkh_relu(acc[i][2][1].x, acc[i][2][1].y);
        oB.w = pkh_relu(acc[i][3][1].x, acc[i][3][1].y);
        *(uint4*)(x1 + (e0 + (size_t)i * P) * 8) = oA;
        *(uint4*)(x1 + (e0 + (size_t)i * P + 1) * 8) = oB;
    }
}

// conv2: rolling-d LDS-staged implicit-GEMM MFMA, async DMA staging.
// d-chunk = 8 -> grid 512 blocks = 2/CU, ALL resident (cap 3/CU at 49.9KB):
// zero occupancy-quantization tail (R12's 1024 blocks ran 768+256 = 1.33x).
// Staging 10 planes per 8 outputs (was 6/4). One barrier per d-step.
__global__ __launch_bounds__(256) void conv2_mfma_kernel(
    const u16* __restrict__ x1, const u16* __restrict__ w2frag,
    const float* __restrict__ b2, u16* __restrict__ x2) {
    __shared__ u16 sm[4 * PLANE * 8];  // 49920 B

    const int tid = threadIdx.x;
    const int lane = tid & 63;
    const int wv = tid >> 6;  // output h-row offset 0..3
    const int q = lane >> 4;
    const int mi = lane & 15;
    const int D0 = (blockIdx.x >> 5) * 8;   // d-chunk base (unpadded out d)
    const int h0 = (blockIdx.x & 31) * 4;   // h-tile base

    // weight A-frags (7KB table, L1-resident)
    f16x8 wf[7];
#pragma unroll
    for (int s = 0; s < 7; ++s)
        wf[s] = *(const f16x8*)(w2frag + (size_t)(s * 64 + lane) * 8);

    // async stage planes D0..D0+2 (padded plane index pd covers rows h0..h0+5)
#pragma unroll
    for (int p = 0; p < 3; ++p) {
        const int pd = D0 + p;
        const int slot = pd & 3;
        const u16* gb = x1 + ((size_t)(pd * P + h0) * P) * 8;
        u16* lb = sm + (size_t)slot * PLANE * 8;
#pragma unroll
        for (int k = 0; k < 3; ++k) {
            const int u0 = wv * 64 + k * 256;
            gload_lds16(gb + (size_t)(u0 + lane) * 8, lb + (size_t)u0 * 8);
        }
        if (wv == 0 && lane < PLANE - 768)
            gload_lds16(gb + (size_t)(768 + lane) * 8, lb + (size_t)768 * 8);
    }
    __syncthreads();

    const float4 bv = *(const float4*)(b2 + q * 4);

#pragma unroll 1
    for (int i = 0; i < 8; ++i) {
        const int dout = D0 + i;

        // async prefetch plane dout+3 into its ring slot (unread this step)
        if (i < 7) {
            const int pd = dout + 3;
            const int slot = pd & 3;
            const u16* gb = x1 + ((size_t)(pd * P + h0) * P) * 8;
            u16* lb = sm + (size_t)slot * PLANE * 8;
#pragma unroll
            for (int k = 0; k < 3; ++k) {
                const int u0 = wv * 64 + k * 256;
                gload_lds16(gb + (size_t)(u0 + lane) * 8, lb + (size_t)u0 * 8);
            }
            if (wv == 0 && lane < PLANE - 768)
                gload_lds16(gb + (size_t)(768 + lane) * 8, lb + (size_t)768 * 8);
        }

        // compute output plane dout from slots (dout..dout+2)&3
        f32x4 acc[8];
#pragma unroll
        for (int t = 0; t < 8; ++t) acc[t] = (f32x4){0.f, 0.f, 0.f, 0.f};

#pragma unroll
        for (int s = 0; s < 7; ++s) {
            int tap = s * 4 + q;
            if (tap > 26) tap = 26;  // pad tap: weight frag is zero there
            const int dz = tap / 9;
            const int rem = tap - dz * 9;
            const int dy = rem / 3;
            const int dx = rem - dy * 3;
            const int slot = (dout + dz) & 3;
            const u16* bp = sm + ((size_t)(slot * 6 + wv + dy) * LROW + (mi + dx)) * 8;
#pragma unroll
            for (int t = 0; t < 8; ++t) {
                f16x8 act = *(const f16x8*)(bp + t * 128);  // +16 voxels
                acc[t] = __builtin_amdgcn_mfma_f32_16x16x32_f16(wf[s], act, acc[t], 0, 0, 0);
            }
        }

        // D: row(oc)=q*4+r, col(voxel)=mi -> lane stores 4 consecutive channels
        const size_t obase = ((size_t)(dout + 1) * P + (h0 + wv + 1)) * P + 1;
#pragma unroll
        for (int t = 0; t < 8; ++t) {
            uint2 o;
            o.x = pkh_relu(acc[t][0] + bv.x, acc[t][1] + bv.y);
            o.y = pkh_relu(acc[t][2] + bv.z, acc[t][3] + bv.w);
            *(uint2*)(x2 + (obase + 16 * t + mi) * 16 + q * 4) = o;
        }

        if (i < 7) __syncthreads();  // drains own DMAs (vmcnt) + publishes plane
    }
}

// conv3: padded x2 [130^3][16] f16 -> out fp32 [128^3] (one batch), tanh.
// 2(d) x 4(h) strip per thread (VOX/8 threads, 1024 blocks -> 16 waves/CU):
// 2x the TLP of the 2x8 strip for +20% issued bytes (288 B/voxel).
__global__ __launch_bounds__(256) void conv3_kernel(
    const u16* __restrict__ x2, const unsigned* __restrict__ w3p,
    const float* __restrict__ b3, float* __restrict__ out) {
    const int t = blockIdx.x * 256 + threadIdx.x;  // VOX/8 threads
    const int w = t & 127;
    const int h0 = ((t >> 7) & 31) * 4;
    const int d0 = (t >> 12) * 2;

    float accA[2][4], accB[2][4];
#pragma unroll
    for (int dd = 0; dd < 2; ++dd)
#pragma unroll
        for (int i = 0; i < 4; ++i) { accA[dd][i] = 0.f; accB[dd][i] = 0.f; }

#pragma unroll 1
    for (int z = 0; z < 4; ++z) {  // padded z-row = d0 + z
        const u16* zb = x2 + ((size_t)((d0 + z) * P + h0) * P + w) * 16;
#pragma unroll
        for (int r = 0; r < 6; ++r) {
            const u16* rp = zb + (size_t)r * (P * 16);
            const uint4 c0l = *(const uint4*)(rp);
            const uint4 c0h = *(const uint4*)(rp + 8);
            const uint4 c1l = *(const uint4*)(rp + 16);
            const uint4 c1h = *(const uint4*)(rp + 24);
            const uint4 c2l = *(const uint4*)(rp + 32);
            const uint4 c2h = *(const uint4*)(rp + 40);
#pragma unroll
            for (int dd = 0; dd < 2; ++dd) {
                const int dz = z - dd;
                if (dz < 0 || dz > 2) continue;  // wave-uniform runtime guard
                const unsigned* wz = w3p + dz * 9 * 8;
#pragma unroll
                for (int dy = 0; dy < 3; ++dy) {
                    const int i = r - dy;
                    if (i < 0 || i > 3) continue;  // compile-time after unroll
                    const unsigned* wp = wz + dy * 3 * 8;
                    float a = accA[dd][i], b = accB[dd][i];
                    a = dot2(c0l.x, wp[0], a);  b = dot2(c0l.y, wp[1], b);
                    a = dot2(c0l.z, wp[2], a);  b = dot2(c0l.w, wp[3], b);
                    a = dot2(c0h.x, wp[4], a);  b = dot2(c0h.y, wp[5], b);
                    a = dot2(c0h.z, wp[6], a);  b = dot2(c0h.w, wp[7], b);
                    a = dot2(c1l.x, wp[8], a);  b = dot2(c1l.y, wp[9], b);
                    a = dot2(c1l.z, wp[10], a); b = dot2(c1l.w, wp[11], b);
                    a = dot2(c1h.x, wp[12], a); b = dot2(c1h.y, wp[13], b);
                    a = dot2(c1h.z, wp[14], a); b = dot2(c1h.w, wp[15], b);
                    a = dot2(c2l.x, wp[16], a); b = dot2(c2l.y, wp[17], b);
                    a = dot2(c2l.z, wp[18], a); b = dot2(c2l.w, wp[19], b);
                    a = dot2(c2h.x, wp[20], a); b = dot2(c2h.y, wp[21], b);
                    a = dot2(c2h.z, wp[22], a); b = dot2(c2h.w, wp[23], b);
                    accA[dd][i] = a; accB[dd][i] = b;
                }
            }
        }
    }
    const float bias = b3[0];
#pragma unroll
    for (int dd = 0; dd < 2; ++dd) {
        const size_t obase = (size_t)((d0 + dd) * 128 + h0) * 128 + w;
#pragma unroll
        for (int i = 0; i < 4; ++i)
            out[obase + (size_t)i * 128] = fast_tanh(accA[dd][i] + accB[dd][i] + bias);
    }
}

extern "C" void kernel_launch(void* const* d_in, const int* in_sizes, int n_in,
                              void* d_out, int out_size, void* d_ws, size_t ws_size,
                              hipStream_t stream) {
    const float* cube = (const float*)d_in[0];
    const float* w1 = (const float*)d_in[1];
    const float* b1 = (const float*)d_in[2];
    const float* w2 = (const float*)d_in[3];
    const float* b2 = (const float*)d_in[4];
    const float* w3 = (const float*)d_in[5];
    const float* b3 = (const float*)d_in[6];
    float* out = (float*)d_out;

    // ws: w2frag@0 (7168B) | w3p@7168 (864B) | w1p@8032 (864B) | x0 @16384 | x1 | x2
    char* ws = (char*)d_ws;
    u16* w2frag = (u16*)ws;
    unsigned* w3p = (unsigned*)(ws + 7168);
    float2* w1p = (float2*)(ws + 8032);
    u16* x0 = (u16*)(ws + 16384);
    u16* x1 = (u16*)(ws + 16384 + (size_t)PVOX * sizeof(u16));
    u16* x2 = (u16*)(ws + 16384 + (size_t)PVOX * sizeof(u16) + (size_t)PVOX * 8 * sizeof(u16));

    for (int b = 0; b < 2; ++b) {
        integrate_kernel<<<dim3((PVOX + 255) / 256), dim3(256), 0, stream>>>(
            cube + (size_t)b * VOX, x0, w1, w2, w3, w2frag, w3p, w1p, x1, x2);
        conv1_kernel<<<dim3(VOX / 8 / 256), dim3(256), 0, stream>>>(x0, w1p, b1, x1);
        conv2_mfma_kernel<<<dim3(512), dim3(256), 0, stream>>>(x1, w2frag, b2, x2);
        conv3_kernel<<<dim3(VOX / 8 / 256), dim3(256), 0, stream>>>(
            x2, w3p, b3, out + (size_t)b * VOX);
    }
}